// Round 17
// baseline (489.529 us; speedup 1.0000x reference)
//
#include <hip/hip_runtime.h>
#include <stdint.h>

#define H_   2048
#define DI_  4096
#define N_   16
#define K_   4
#define R_   128
#define FF_  5632
#define B_   2
#define S_   1024
#define MROWS (B_*S_)   // 2048
#define PCH  32          // time chunks for scan
#define CSTEPS (S_/PCH)  // 32 steps per chunk

typedef float f32x4 __attribute__((ext_vector_type(4)));
typedef float f32x2 __attribute__((ext_vector_type(2)));
typedef __bf16 bf16x8 __attribute__((ext_vector_type(8)));

#define LOG2E 1.4426950408889634f
#define LN2   0.6931471805599453f

__device__ __forceinline__ unsigned short f2bf(float f) {
    union { float f; unsigned u; } v; v.f = f;
    unsigned r = v.u + 0x7fffu + ((v.u >> 16) & 1u);
    return (unsigned short)(r >> 16);
}

__device__ __forceinline__ float bf2f(unsigned short u) {
    union { unsigned u; float f; } v; v.u = ((unsigned)u) << 16;
    return v.f;
}

__device__ __forceinline__ float fexp2(float x) { return __builtin_amdgcn_exp2f(x); }
__device__ __forceinline__ float flog2(float x) { return __builtin_amdgcn_logf(x); }

__device__ __forceinline__ float softplus2(float v) {
    return (v > 20.f) ? v : LN2 * flog2(1.f + fexp2(v * LOG2E));
}

__device__ __forceinline__ void gload16(const void* g, void* lds) {
    __builtin_amdgcn_global_load_lds(
        (const __attribute__((address_space(1))) unsigned int*)(uintptr_t)g,
        (__attribute__((address_space(3))) unsigned int*)(unsigned int)(uintptr_t)lds,
        16, 0, 0);
}

// ---------------- GEMM 128x128 (for small-N shapes): C = A @ Bt^T ----------------
__global__ __launch_bounds__(256, 2)
void gemm_bt(const unsigned short* __restrict__ A, const unsigned short* __restrict__ Bt,
             void* __restrict__ Cv, int M, int N, int K, int Kc, int obf)
{
    __shared__ __align__(16) unsigned short As[128 * 64];
    __shared__ __align__(16) unsigned short Bs[128 * 64];
    const int t = threadIdx.x;
    const int l = t & 63;
    const int wv = t >> 6;

    int nwg = gridDim.x * gridDim.y;
    int wg = blockIdx.y * gridDim.x + blockIdx.x;
    if ((nwg & 7) == 0) {
        int q = nwg >> 3;
        wg = (wg & 7) * q + (wg >> 3);
    }
    const int bx = wg / gridDim.y;
    const int by = wg % gridDim.y;
    const long m0 = (long)by * 128;
    const long n0 = (long)bx * 128;
    const int wm = (wv >> 1) * 64;
    const int wn = (wv & 1) * 64;
    const long kstart = (long)blockIdx.z * Kc;
    const long cbase = (long)blockIdx.z * M * (long)N;

    f32x4 acc[4][4] = {};

    const int tr = t >> 3;
    const int cs = (t & 7) ^ (tr & 7);
    const unsigned short* gA = A + (m0 + tr) * (long)K + kstart + cs * 8;
    const unsigned short* gB = Bt + (n0 + tr) * (long)K + kstart + cs * 8;
    const unsigned ldsbase = (unsigned)(t & 192) * 16;

    for (int kt = 0; kt < Kc; kt += 64) {
#pragma unroll
        for (int j = 0; j < 4; ++j) {
            gload16(gA + (long)j * 32 * K, (char*)As + j * 4096 + ldsbase);
            gload16(gB + (long)j * 32 * K, (char*)Bs + j * 4096 + ldsbase);
        }
        gA += 64; gB += 64;
        __syncthreads();
#pragma unroll
        for (int k0 = 0; k0 < 2; ++k0) {
            bf16x8 af[4], bfr[4];
#pragma unroll
            for (int i = 0; i < 4; ++i) {
                int rowa = wm + i * 16 + (l & 15);
                int ca = (k0 * 4 + (l >> 4)) ^ (rowa & 7);
                af[i] = *(const bf16x8*)(As + rowa * 64 + ca * 8);
                int rowb = wn + i * 16 + (l & 15);
                int cb = (k0 * 4 + (l >> 4)) ^ (rowb & 7);
                bfr[i] = *(const bf16x8*)(Bs + rowb * 64 + cb * 8);
            }
#pragma unroll
            for (int i = 0; i < 4; ++i)
#pragma unroll
                for (int jn = 0; jn < 4; ++jn)
                    acc[i][jn] = __builtin_amdgcn_mfma_f32_16x16x32_bf16(
                        af[i], bfr[jn], acc[i][jn], 0, 0, 0);
        }
        __syncthreads();
    }

    const int crow = (l >> 4) * 4;
    const int ccol = l & 15;
    float* Cf = (float*)Cv + cbase;
    unsigned short* Cb = (unsigned short*)Cv + cbase;
#pragma unroll
    for (int i = 0; i < 4; ++i) {
#pragma unroll
        for (int jn = 0; jn < 4; ++jn) {
            long row = m0 + wm + i * 16 + crow;
            long col = n0 + wn + jn * 16 + ccol;
            if (obf) {
                unsigned short* cp = Cb + row * (long)N + col;
#pragma unroll
                for (int q = 0; q < 4; ++q) cp[(long)q * N] = f2bf(acc[i][jn][q]);
            } else {
                float* cp = Cf + row * (long)N + col;
#pragma unroll
                for (int q = 0; q < 4; ++q) cp[(long)q * N] = acc[i][jn][q];
            }
        }
    }
}

// ======== GEMM 256x256, 8 waves, BK=64, 8-phase snake-quadrant schedule ========
// m201-style: 4 phases/K-tile. Quad order (0,0)(0,1)(1,1)(1,0).
// Region deaths: A-qa0@P0, B-qb1@P1, A-qa1@P2, B-qb0@P3 (re-read at P3).
// Stage plan: P0->Bqb0(t+1,obuf); P1->Aqa0(t+2,buf); P2->Bqb1(t+2,buf);
//             P3->Aqa1(t+2,buf). vmcnt(4) once/tile at P3 (never 0).
__global__ __launch_bounds__(512, 1)
void gemm_bt256(const unsigned short* __restrict__ A, const unsigned short* __restrict__ Bt,
                void* __restrict__ Cv, int M, int N, int K, int Kc, int obf)
{
    __shared__ __align__(16) unsigned short As[2][256 * 64];
    __shared__ __align__(16) unsigned short Bs[2][256 * 64];
    const int t = threadIdx.x;
    const int l = t & 63;
    const int wv = t >> 6;
    const int wm = wv >> 2;
    const int wn = wv & 3;

    int nwg = gridDim.x * gridDim.y;
    int wg = blockIdx.y * gridDim.x + blockIdx.x;
    if ((nwg & 7) == 0) {
        int q = nwg >> 3;
        wg = (wg & 7) * q + (wg >> 3);
    }
    const int bx = wg / gridDim.y;
    const int by = wg % gridDim.y;
    const long m0 = (long)by * 256;
    const long n0 = (long)bx * 256;
    const long kstart = (long)blockIdx.z * Kc;
    const long cbase = (long)blockIdx.z * M * (long)N;

    f32x4 acc[8][4] = {};
    const int NT = Kc >> 6;           // >= 2 for all shapes used
    const int cs8 = (l & 7) ^ (l >> 3);

    // Stage one 16KB region (2 gload16/thread). base_row always multiple of 8.
    auto stageA = [&](int qa, int kt2, int bufi) {
#pragma unroll
        for (int i = 0; i < 2; ++i) {
            const int r16 = wv * 2 + i;
            const int base_row = ((r16 >> 3) << 7) + (qa << 6) + ((r16 & 7) << 3);
            gload16(A + (m0 + base_row + (l >> 3)) * (long)K + kstart + (long)kt2 * 64 + cs8 * 8,
                    &As[bufi][base_row * 64 + l * 8]);
        }
    };
    auto stageB = [&](int qb, int kt2, int bufi) {
#pragma unroll
        for (int i = 0; i < 2; ++i) {
            const int r16 = wv * 2 + i;
            const int base_row = ((r16 >> 2) << 6) + (qb << 5) + ((r16 & 3) << 3);
            gload16(Bt + (n0 + base_row + (l >> 3)) * (long)K + kstart + (long)kt2 * 64 + cs8 * 8,
                    &Bs[bufi][base_row * 64 + l * 8]);
        }
    };

    // Prologue: R0(0) R1(0) R2(0) R3(0) R0(1) R1(1) R2(1); vmcnt(6); barrier.
    stageA(0, 0, 0); stageB(1, 0, 0); stageA(1, 0, 0); stageB(0, 0, 0);
    stageA(0, 1, 1); stageB(1, 1, 1); stageA(1, 1, 1);
    asm volatile("s_waitcnt vmcnt(6)" ::: "memory");
    __builtin_amdgcn_sched_barrier(0);
    __builtin_amdgcn_s_barrier();
    __builtin_amdgcn_sched_barrier(0);

    for (int kt = 0; kt < NT; ++kt) {
        const int buf = kt & 1, obuf = buf ^ 1;
        const int kn1 = (kt + 1 < NT) ? kt + 1 : kt;
        const int kn2 = (kt + 2 < NT) ? kt + 2 : NT - 1;
        bf16x8 afq[4][2], bfq[2][2];

        // ---- read helpers (inline per phase) ----
        // P0: quad (0,0): read a-qa0 (8), b-qb0 (4); stage B-qb0(kt+1)->obuf
#pragma unroll
        for (int m2 = 0; m2 < 4; ++m2)
#pragma unroll
            for (int ks = 0; ks < 2; ++ks) {
                int rowa = wm * 128 + m2 * 16 + (l & 15);
                int ca = (ks * 4 + (l >> 4)) ^ (rowa & 7);
                afq[m2][ks] = *(const bf16x8*)(&As[buf][rowa * 64 + ca * 8]);
            }
#pragma unroll
        for (int n2 = 0; n2 < 2; ++n2)
#pragma unroll
            for (int ks = 0; ks < 2; ++ks) {
                int rowb = wn * 64 + n2 * 16 + (l & 15);
                int cb = (ks * 4 + (l >> 4)) ^ (rowb & 7);
                bfq[n2][ks] = *(const bf16x8*)(&Bs[buf][rowb * 64 + cb * 8]);
            }
        stageB(0, kn1, obuf);
        __builtin_amdgcn_s_barrier();
        asm volatile("s_waitcnt lgkmcnt(0)" ::: "memory");
        __builtin_amdgcn_sched_barrier(0);
        __builtin_amdgcn_s_setprio(1);
#pragma unroll
        for (int m2 = 0; m2 < 4; ++m2)
#pragma unroll
            for (int n2 = 0; n2 < 2; ++n2)
#pragma unroll
                for (int ks = 0; ks < 2; ++ks)
                    acc[m2][n2] = __builtin_amdgcn_mfma_f32_16x16x32_bf16(
                        afq[m2][ks], bfq[n2][ks], acc[m2][n2], 0, 0, 0);
        __builtin_amdgcn_s_setprio(0);
        __builtin_amdgcn_sched_barrier(0);
        __builtin_amdgcn_s_barrier();
        __builtin_amdgcn_sched_barrier(0);

        // P1: quad (0,1): reuse a-qa0, read b-qb1 (4); stage A-qa0(kt+2)->buf
#pragma unroll
        for (int n2 = 0; n2 < 2; ++n2)
#pragma unroll
            for (int ks = 0; ks < 2; ++ks) {
                int rowb = wn * 64 + (2 + n2) * 16 + (l & 15);
                int cb = (ks * 4 + (l >> 4)) ^ (rowb & 7);
                bfq[n2][ks] = *(const bf16x8*)(&Bs[buf][rowb * 64 + cb * 8]);
            }
        stageA(0, kn2, buf);
        __builtin_amdgcn_s_barrier();
        asm volatile("s_waitcnt lgkmcnt(0)" ::: "memory");
        __builtin_amdgcn_sched_barrier(0);
        __builtin_amdgcn_s_setprio(1);
#pragma unroll
        for (int m2 = 0; m2 < 4; ++m2)
#pragma unroll
            for (int n2 = 0; n2 < 2; ++n2)
#pragma unroll
                for (int ks = 0; ks < 2; ++ks)
                    acc[m2][2 + n2] = __builtin_amdgcn_mfma_f32_16x16x32_bf16(
                        afq[m2][ks], bfq[n2][ks], acc[m2][2 + n2], 0, 0, 0);
        __builtin_amdgcn_s_setprio(0);
        __builtin_amdgcn_sched_barrier(0);
        __builtin_amdgcn_s_barrier();
        __builtin_amdgcn_sched_barrier(0);

        // P2: quad (1,1): read a-qa1 (8), reuse b-qb1; stage B-qb1(kt+2)->buf
#pragma unroll
        for (int m2 = 0; m2 < 4; ++m2)
#pragma unroll
            for (int ks = 0; ks < 2; ++ks) {
                int rowa = wm * 128 + (4 + m2) * 16 + (l & 15);
                int ca = (ks * 4 + (l >> 4)) ^ (rowa & 7);
                afq[m2][ks] = *(const bf16x8*)(&As[buf][rowa * 64 + ca * 8]);
            }
        stageB(1, kn2, buf);
        __builtin_amdgcn_s_barrier();
        asm volatile("s_waitcnt lgkmcnt(0)" ::: "memory");
        __builtin_amdgcn_sched_barrier(0);
        __builtin_amdgcn_s_setprio(1);
#pragma unroll
        for (int m2 = 0; m2 < 4; ++m2)
#pragma unroll
            for (int n2 = 0; n2 < 2; ++n2)
#pragma unroll
                for (int ks = 0; ks < 2; ++ks)
                    acc[4 + m2][2 + n2] = __builtin_amdgcn_mfma_f32_16x16x32_bf16(
                        afq[m2][ks], bfq[n2][ks], acc[4 + m2][2 + n2], 0, 0, 0);
        __builtin_amdgcn_s_setprio(0);
        __builtin_amdgcn_sched_barrier(0);
        __builtin_amdgcn_s_barrier();
        __builtin_amdgcn_sched_barrier(0);

        // P3: quad (1,0): reuse a-qa1, re-read b-qb0 (4); stage A-qa1(kt+2)->buf;
        //     vmcnt(4) once per tile (leaves last 2 stages in flight).
#pragma unroll
        for (int n2 = 0; n2 < 2; ++n2)
#pragma unroll
            for (int ks = 0; ks < 2; ++ks) {
                int rowb = wn * 64 + n2 * 16 + (l & 15);
                int cb = (ks * 4 + (l >> 4)) ^ (rowb & 7);
                bfq[n2][ks] = *(const bf16x8*)(&Bs[buf][rowb * 64 + cb * 8]);
            }
        stageA(1, kn2, buf);
        __builtin_amdgcn_s_barrier();
        asm volatile("s_waitcnt lgkmcnt(0)" ::: "memory");
        __builtin_amdgcn_sched_barrier(0);
        __builtin_amdgcn_s_setprio(1);
#pragma unroll
        for (int m2 = 0; m2 < 4; ++m2)
#pragma unroll
            for (int n2 = 0; n2 < 2; ++n2)
#pragma unroll
                for (int ks = 0; ks < 2; ++ks)
                    acc[4 + m2][n2] = __builtin_amdgcn_mfma_f32_16x16x32_bf16(
                        afq[m2][ks], bfq[n2][ks], acc[4 + m2][n2], 0, 0, 0);
        __builtin_amdgcn_s_setprio(0);
        asm volatile("s_waitcnt vmcnt(4)" ::: "memory");
        __builtin_amdgcn_sched_barrier(0);
        __builtin_amdgcn_s_barrier();
        __builtin_amdgcn_sched_barrier(0);
    }

    const int crow = (l >> 4) * 4;
    const int ccol = l & 15;
    float* Cf = (float*)Cv + cbase;
    unsigned short* Cb = (unsigned short*)Cv + cbase;
#pragma unroll
    for (int mf = 0; mf < 8; ++mf) {
#pragma unroll
        for (int nf = 0; nf < 4; ++nf) {
            long row = m0 + wm * 128 + mf * 16 + crow;
            long col = n0 + wn * 64 + nf * 16 + ccol;
            if (obf) {
                unsigned short* cp = Cb + row * (long)N + col;
#pragma unroll
                for (int q = 0; q < 4; ++q) cp[(long)q * N] = f2bf(acc[mf][nf][q]);
            } else {
                float* cp = Cf + row * (long)N + col;
#pragma unroll
                for (int q = 0; q < 4; ++q) cp[(long)q * N] = acc[mf][nf][q];
            }
        }
    }
}

// ---------------- f32 -> bf16 convert ----------------
__global__ __launch_bounds__(256)
void cvt_bf16(const float* __restrict__ x, unsigned short* __restrict__ y, long n)
{
    long i = ((long)blockIdx.x * 256 + threadIdx.x) * 4;
    if (i >= n) return;
    float4 v = *(const float4*)(x + i);
    ushort4 o;
    o.x = f2bf(v.x); o.y = f2bf(v.y); o.z = f2bf(v.z); o.w = f2bf(v.w);
    *(ushort4*)(y + i) = o;
}

// w_x [160,4096] -> bf16 padded to [256,4096] (zeros)
__global__ __launch_bounds__(256)
void cvt_pad_wx(const float* __restrict__ x, unsigned short* __restrict__ y)
{
    long i = ((long)blockIdx.x * 256 + threadIdx.x) * 4;
    int row = (int)(i >> 12);
    ushort4 o;
    if (row < 160) {
        float4 v = *(const float4*)(x + i);
        o.x = f2bf(v.x); o.y = f2bf(v.y); o.z = f2bf(v.z); o.w = f2bf(v.w);
    } else { o.x = 0; o.y = 0; o.z = 0; o.w = 0; }
    *(ushort4*)(y + i) = o;
}

// ---------------- RMSNorm over H=2048, output bf16 ----------------
__global__ __launch_bounds__(256)
void rmsnorm_cast(const float* __restrict__ x, const float* __restrict__ w,
                  unsigned short* __restrict__ out)
{
    const long row = blockIdx.x;
    const float* xr = x + row * H_ + threadIdx.x * 8;
    float4 v0 = *(const float4*)xr;
    float4 v1 = *(const float4*)(xr + 4);
    float xv[8] = {v0.x, v0.y, v0.z, v0.w, v1.x, v1.y, v1.z, v1.w};
    float s = 0.f;
#pragma unroll
    for (int j = 0; j < 8; ++j) s += xv[j] * xv[j];
#pragma unroll
    for (int m = 32; m; m >>= 1) s += __shfl_xor(s, m);
    __shared__ float red[4];
    if ((threadIdx.x & 63) == 0) red[threadIdx.x >> 6] = s;
    __syncthreads();
    s = red[0] + red[1] + red[2] + red[3];
    float inv = rsqrtf(s * (1.f / H_) + 1e-6f);
    const float* wr = w + threadIdx.x * 8;
    unsigned short* op = out + row * H_ + threadIdx.x * 8;
    ushort4 o0, o1;
    o0.x = f2bf(xv[0] * inv * wr[0]); o0.y = f2bf(xv[1] * inv * wr[1]);
    o0.z = f2bf(xv[2] * inv * wr[2]); o0.w = f2bf(xv[3] * inv * wr[3]);
    o1.x = f2bf(xv[4] * inv * wr[4]); o1.y = f2bf(xv[5] * inv * wr[5]);
    o1.z = f2bf(xv[6] * inv * wr[6]); o1.w = f2bf(xv[7] * inv * wr[7]);
    *(ushort4*)op = o0;
    *(ushort4*)(op + 4) = o1;
}

// --------- hidden = a + sum_4(mx bf16) ; h = rmsnorm(hidden) bf16 ----------
__global__ __launch_bounds__(256)
void add_rmsnorm(const float* __restrict__ a, const unsigned short* __restrict__ mx,
                 const float* __restrict__ w, float* __restrict__ hid,
                 unsigned short* __restrict__ hb)
{
    const long row = blockIdx.x;
    const long off = row * H_ + threadIdx.x * 8;
    float xv[8];
    {
        float4 a0 = *(const float4*)(a + off);
        float4 a1 = *(const float4*)(a + off + 4);
        xv[0] = a0.x; xv[1] = a0.y; xv[2] = a0.z; xv[3] = a0.w;
        xv[4] = a1.x; xv[5] = a1.y; xv[6] = a1.z; xv[7] = a1.w;
    }
#pragma unroll
    for (int z = 0; z < 4; ++z) {
        const unsigned short* mz = mx + (long)z * MROWS * H_ + off;
        ushort4 b0 = *(const ushort4*)mz;
        ushort4 b1 = *(const ushort4*)(mz + 4);
        xv[0] += bf2f(b0.x); xv[1] += bf2f(b0.y); xv[2] += bf2f(b0.z); xv[3] += bf2f(b0.w);
        xv[4] += bf2f(b1.x); xv[5] += bf2f(b1.y); xv[6] += bf2f(b1.z); xv[7] += bf2f(b1.w);
    }
    float s = 0.f;
#pragma unroll
    for (int j = 0; j < 8; ++j) s += xv[j] * xv[j];
#pragma unroll
    for (int m = 32; m; m >>= 1) s += __shfl_xor(s, m);
    __shared__ float red[4];
    if ((threadIdx.x & 63) == 0) red[threadIdx.x >> 6] = s;
    __syncthreads();
    s = red[0] + red[1] + red[2] + red[3];
    float inv = rsqrtf(s * (1.f / H_) + 1e-6f);
    float4 h0, h1;
    h0.x = xv[0]; h0.y = xv[1]; h0.z = xv[2]; h0.w = xv[3];
    h1.x = xv[4]; h1.y = xv[5]; h1.z = xv[6]; h1.w = xv[7];
    *(float4*)(hid + off) = h0;
    *(float4*)(hid + off + 4) = h1;
    const float* wr = w + threadIdx.x * 8;
    ushort4 o0, o1;
    o0.x = f2bf(xv[0] * inv * wr[0]); o0.y = f2bf(xv[1] * inv * wr[1]);
    o0.z = f2bf(xv[2] * inv * wr[2]); o0.w = f2bf(xv[3] * inv * wr[3]);
    o1.x = f2bf(xv[4] * inv * wr[4]); o1.y = f2bf(xv[5] * inv * wr[5]);
    o1.z = f2bf(xv[6] * inv * wr[6]); o1.w = f2bf(xv[7] * inv * wr[7]);
    *(ushort4*)(hb + off) = o0;
    *(ushort4*)(hb + off + 4) = o1;
}

// -------- causal depthwise conv(K=4) + bias + SiLU, 4 channels/thread --------
__global__ __launch_bounds__(256)
void conv_silu(const unsigned short* __restrict__ proj, const float* __restrict__ cw,
               const float* __restrict__ cb, unsigned short* __restrict__ ub)
{
    long i = ((long)blockIdx.x * 256 + threadIdx.x) * 4;
    int d = (int)(i & (DI_ - 1));
    long sd = i >> 12;
    int s = (int)(sd & (S_ - 1));
    long rb = sd * (2 * DI_) + d;
    ushort4 x0 = *(const ushort4*)(proj + rb);
    ushort4 x1 = {0, 0, 0, 0}, x2 = {0, 0, 0, 0}, x3 = {0, 0, 0, 0};
    if (s >= 1) x1 = *(const ushort4*)(proj + rb - 2 * DI_);
    if (s >= 2) x2 = *(const ushort4*)(proj + rb - 4 * DI_);
    if (s >= 3) x3 = *(const ushort4*)(proj + rb - 6 * DI_);
    float4 bias = *(const float4*)(cb + d);
    unsigned short xs0[4] = {x0.x, x0.y, x0.z, x0.w};
    unsigned short xs1[4] = {x1.x, x1.y, x1.z, x1.w};
    unsigned short xs2[4] = {x2.x, x2.y, x2.z, x2.w};
    unsigned short xs3[4] = {x3.x, x3.y, x3.z, x3.w};
    float bs[4] = {bias.x, bias.y, bias.z, bias.w};
    unsigned short os[4];
#pragma unroll
    for (int j = 0; j < 4; ++j) {
        float4 wj = *(const float4*)(cw + (d + j) * 4);
        float acc = bs[j] + wj.w * bf2f(xs0[j]);
        if (s >= 1) acc += wj.z * bf2f(xs1[j]);
        if (s >= 2) acc += wj.y * bf2f(xs2[j]);
        if (s >= 3) acc += wj.x * bf2f(xs3[j]);
        float r = acc / (1.f + __expf(-acc));
        os[j] = f2bf(r);
    }
    ushort4 o; o.x = os[0]; o.y = os[1]; o.z = os[2]; o.w = os[3];
    *(ushort4*)(ub + i) = o;
}

// ------ segment rmsnorms on ssm_p partial slabs (8 x [2048,256] bf16) ------
__global__ __launch_bounds__(256)
void ssm_norms(const unsigned short* __restrict__ ssmp, const float* __restrict__ wdt,
               const float* __restrict__ wb, const float* __restrict__ wc,
               unsigned short* __restrict__ trb, float* __restrict__ Bm,
               float* __restrict__ Cm)
{
    const long row = (long)blockIdx.x * 4 + (threadIdx.x >> 6);
    const int l = threadIdx.x & 63;
    float x0 = 0.f, x1 = 0.f, xb = 0.f, xc = 0.f;
#pragma unroll
    for (int z = 0; z < 8; ++z) {
        const unsigned short* rp = ssmp + (long)z * (MROWS * 256) + row * 256;
        x0 += bf2f(rp[l]);
        x1 += bf2f(rp[64 + l]);
        xb += bf2f(rp[128 + (l & 15)]);
        xc += bf2f(rp[144 + (l & 15)]);
    }
    float s = x0 * x0 + x1 * x1;
#pragma unroll
    for (int m = 32; m; m >>= 1) s += __shfl_xor(s, m);
    float inv = rsqrtf(s * (1.f / R_) + 1e-6f);
    trb[row * R_ + l] = f2bf(x0 * inv * wdt[l]);
    trb[row * R_ + 64 + l] = f2bf(x1 * inv * wdt[64 + l]);

    float sb = xb * xb, sc = xc * xc;
#pragma unroll
    for (int m = 8; m; m >>= 1) { sb += __shfl_xor(sb, m); sc += __shfl_xor(sc, m); }
    float invb = rsqrtf(sb * (1.f / N_) + 1e-6f);
    float invc = rsqrtf(sc * (1.f / N_) + 1e-6f);
    if (l < 16) {
        Bm[row * N_ + l] = xb * invb * wb[l];
        Cm[row * N_ + l] = xc * invc * wc[l];
    }
}

// =======================================================================
// Selective scan v4
// =======================================================================

__global__ __launch_bounds__(256)
void scan_partA(const unsigned short* __restrict__ ub, const unsigned short* __restrict__ dtraw,
                const float* __restrict__ bdt, const float* __restrict__ Bm,
                const float* __restrict__ A_log,
                float* __restrict__ TRH, float* __restrict__ TRS)
{
    const int w = __builtin_amdgcn_readfirstlane(threadIdx.x >> 6);
    const int l = threadIdx.x & 63;
    const int task = blockIdx.x * 4 + w;
    const int dchunk = task >> 5;
    const int p = task & 31;
    const int gch0 = dchunk * 64;
    const int batch = gch0 >> 12;
    const int d0 = gch0 & (DI_ - 1);
    const int d = d0 + l;
    const long bS = (long)batch * S_;
    const int t0 = p * CSTEPS;

    float Av2[16];
#pragma unroll
    for (int n = 0; n < 16; ++n)
        Av2[n] = -fexp2(A_log[(long)d * N_ + n] * LOG2E) * LOG2E;
    const float bias = bdt[d];

    float h[16];
#pragma unroll
    for (int n = 0; n < 16; ++n) h[n] = 0.f;
    float sdt = 0.f;

    float uN = bf2f(ub[(bS + t0) * DI_ + d]);
    float tN = bf2f(dtraw[(bS + t0) * DI_ + d]);
    float BN[16];
    {
        const float* Bp = Bm + (bS + t0) * N_;
#pragma unroll
        for (int n = 0; n < 16; ++n) BN[n] = Bp[n];
    }

    for (int s = 0; s < CSTEPS; ++s) {
        float uC = uN, tC = tN;
        float BC[16];
#pragma unroll
        for (int n = 0; n < 16; ++n) BC[n] = BN[n];
        if (s + 1 < CSTEPS) {
            long r2 = bS + t0 + s + 1;
            uN = bf2f(ub[r2 * DI_ + d]);
            tN = bf2f(dtraw[r2 * DI_ + d]);
            const float* Bp = Bm + r2 * N_;
#pragma unroll
            for (int n = 0; n < 16; ++n) BN[n] = Bp[n];
        }
        float dt = softplus2(tC + bias);
        float dtu = dt * uC;
        sdt += dt;
#pragma unroll
        for (int n = 0; n < 16; ++n) {
            float e = fexp2(dt * Av2[n]);
            h[n] = fmaf(e, h[n], dtu * BC[n]);
        }
    }
    float* hp = &TRH[(long)(gch0 + l) * (PCH * 16) + p * 16];
#pragma unroll
    for (int n = 0; n < 16; ++n) hp[n] = h[n];
    TRS[(long)(gch0 + l) * PCH + p] = sdt;
}

__global__ __launch_bounds__(256)
void scan_combine(const float* __restrict__ A_log, const float* __restrict__ TRS,
                  float* __restrict__ TRH)
{
    const int tid = blockIdx.x * 256 + threadIdx.x;
    const int gch = tid >> 4, n = tid & 15;
    const int d = gch & (DI_ - 1);
    const float Av = -__expf(A_log[(long)d * N_ + n]);
    const float* sp = TRS + (long)gch * PCH;
    float* hp = TRH + (long)gch * (PCH * 16) + n;
    float h = 0.f;
#pragma unroll
    for (int p = 0; p < PCH; ++p) {
        float hl = hp[p * 16];
        float e = __expf(Av * sp[p]);
        hp[p * 16] = h;
        h = hl + e * h;
    }
}

__global__ __launch_bounds__(256)
void scan_partC(const unsigned short* __restrict__ ub, const unsigned short* __restrict__ dtraw,
                const float* __restrict__ bdt, const float* __restrict__ Bm,
                const float* __restrict__ Cm, const float* __restrict__ A_log,
                const float* __restrict__ Dskip, const unsigned short* __restrict__ proj,
                const float* __restrict__ TRH, unsigned short* __restrict__ yb)
{
    const int w = __builtin_amdgcn_readfirstlane(threadIdx.x >> 6);
    const int l = threadIdx.x & 63;
    const int task = blockIdx.x * 4 + w;
    const int dchunk = task >> 5;
    const int p = task & 31;
    const int gch0 = dchunk * 64;
    const int batch = gch0 >> 12;
    const int d0 = gch0 & (DI_ - 1);
    const int d = d0 + l;
    const long bS = (long)batch * S_;
    const int t0 = p * CSTEPS;

    float Av2[16];
#pragma unroll
    for (int n = 0; n < 16; ++n)
        Av2[n] = -fexp2(A_log[(long)d * N_ + n] * LOG2E) * LOG2E;
    const float bias = bdt[d];
    const float Dv = Dskip[d];

    float h[16];
    {
        const float* hp = &TRH[(long)(gch0 + l) * (PCH * 16) + p * 16];
#pragma unroll
        for (int n = 0; n < 16; ++n) h[n] = hp[n];
    }

    float uN = bf2f(ub[(bS + t0) * DI_ + d]);
    float tN = bf2f(dtraw[(bS + t0) * DI_ + d]);
    float gN = bf2f(proj[(bS + t0) * (2L * DI_) + DI_ + d]);
    float BN[16], CN[16];
    {
        const float* Bp = Bm + (bS + t0) * N_;
        const float* Cp = Cm + (bS + t0) * N_;
#pragma unroll
        for (int n = 0; n < 16; ++n) { BN[n] = Bp[n]; CN[n] = Cp[n]; }
    }

    for (int s = 0; s < CSTEPS; ++s) {
        float uC = uN, tC = tN, gC = gN;
        float BC[16], CC_[16];
#pragma unroll
        for (int n = 0; n < 16; ++n) { BC[n] = BN[n]; CC_[n] = CN[n]; }
        if (s + 1 < CSTEPS) {
            long r2 = bS + t0 + s + 1;
            uN = bf2f(ub[r2 * DI_ + d]);
            tN = bf2f(dtraw[r2 * DI_ + d]);
            gN = bf2f(proj[r2 * (2L * DI_) + DI_ + d]);
            const float* Bp = Bm + r2 * N_;
            const float* Cp = Cm + r2 * N_;
#pragma unroll
            for (int n = 0; n < 16; ++n) { BN[n] = Bp[n]; CN[n] = Cp[n]; }
        }
        float dt = softplus2(tC + bias);
        float dtu = dt * uC;
        float y = uC * Dv;
#pragma unroll
        for (int n = 0; n < 16; ++n) {
            float e = fexp2(dt * Av2[n]);
            h[n] = fmaf(e, h[n], dtu * BC[n]);
            y = fmaf(h[n], CC_[n], y);
        }
        float eg = fexp2(-gC * LOG2E);
        float sl = gC * __builtin_amdgcn_rcpf(1.f + eg);
        yb[(bS + t0 + s) * DI_ + d] = f2bf(y * sl);
    }
}

// --- ffact = silu(gate)*up from combined gate/up GEMM (2 split-K slabs) ---
__global__ __launch_bounds__(256)
void silu_mul2(const unsigned short* __restrict__ gfu, unsigned short* __restrict__ out,
               long n)
{
    long i = ((long)blockIdx.x * 256 + threadIdx.x) * 4;
    if (i >= n) return;
    long m = i / FF_;
    int f = (int)(i - m * FF_);
    const long NW = 2L * FF_;
    const unsigned short* r0 = gfu + m * NW;
    const unsigned short* r1 = gfu + (long)MROWS * NW + m * NW;
    ushort4 g0 = *(const ushort4*)(r0 + f);
    ushort4 g1 = *(const ushort4*)(r1 + f);
    ushort4 u0 = *(const ushort4*)(r0 + FF_ + f);
    ushort4 u1 = *(const ushort4*)(r1 + FF_ + f);
    float gv[4] = {bf2f(g0.x) + bf2f(g1.x), bf2f(g0.y) + bf2f(g1.y),
                   bf2f(g0.z) + bf2f(g1.z), bf2f(g0.w) + bf2f(g1.w)};
    float uv[4] = {bf2f(u0.x) + bf2f(u1.x), bf2f(u0.y) + bf2f(u1.y),
                   bf2f(u0.z) + bf2f(u1.z), bf2f(u0.w) + bf2f(u1.w)};
    unsigned short os[4];
#pragma unroll
    for (int j = 0; j < 4; ++j)
        os[j] = f2bf(gv[j] / (1.f + __expf(-gv[j])) * uv[j]);
    ushort4 o; o.x = os[0]; o.y = os[1]; o.z = os[2]; o.w = os[3];
    *(ushort4*)(out + i) = o;
}

// ---------------- out = hidden + sum_4(ff bf16)  (split-K fuse) ----------------
__global__ __launch_bounds__(256)
void final_add(const float* __restrict__ a, const unsigned short* __restrict__ b,
               float* __restrict__ y, long n)
{
    long i = ((long)blockIdx.x * 256 + threadIdx.x) * 4;
    if (i >= n) return;
    float4 av = *(const float4*)(a + i);
    float4 o = av;
#pragma unroll
    for (int z = 0; z < 4; ++z) {
        ushort4 bv = *(const ushort4*)(b + (long)z * MROWS * H_ + i);
        o.x += bf2f(bv.x); o.y += bf2f(bv.y); o.z += bf2f(bv.z); o.w += bf2f(bv.w);
    }
    *(float4*)(y + i) = o;
}

extern "C" void kernel_launch(void* const* d_in, const int* in_sizes, int n_in,
                              void* d_out, int out_size, void* d_ws, size_t ws_size,
                              hipStream_t stream)
{
    const float* hs     = (const float*)d_in[0];
    const float* ln_in  = (const float*)d_in[1];
    const float* w_in   = (const float*)d_in[2];
    const float* conv_w = (const float*)d_in[3];
    const float* conv_b = (const float*)d_in[4];
    const float* w_x    = (const float*)d_in[5];
    const float* dt_ln  = (const float*)d_in[6];
    const float* b_ln   = (const float*)d_in[7];
    const float* c_ln   = (const float*)d_in[8];
    const float* w_dt   = (const float*)d_in[9];
    const float* b_dt   = (const float*)d_in[10];
    const float* A_log  = (const float*)d_in[11];
    const float* Dskip  = (const float*)d_in[12];
    const float* w_out  = (const float*)d_in[13];
    const float* ln_ff  = (const float*)d_in[14];
    const float* w_gate = (const float*)d_in[15];
    const float* w_up   = (const float*)d_in[16];
    const float* w_down = (const float*)d_in[17];
    float* out = (float*)d_out;
    char* ws = (char*)d_ws;

    // Arena (lifetime-based reuse)
    unsigned short* WB    = (unsigned short*)(ws + 0L);            // 33.5MB weights bf16
    unsigned short* XB    = (unsigned short*)(ws + 33554432L);     // 8.4MB (xb / hb)
    unsigned short* PROJ  = (unsigned short*)(ws + 41943040L);     // bf16 33.6MB (2-7)
    unsigned short* MIX   = (unsigned short*)(ws + 41943040L);     // bf16 4 slabs (8-9)
    unsigned short* GFU   = (unsigned short*)(ws + 41943040L);     // bf16 2 slabs 92.2MB (10-11)
    unsigned short* FFT   = (unsigned short*)(ws + 41943040L);     // bf16 4 slabs (12)
    unsigned short* UB    = (unsigned short*)(ws + 142606336L);    // bf16 16.8MB (3-7)
    float*          HID   = (float*)(ws + 142606336L);             // f32 16.8MB (9-12)
    unsigned short* TRB   = (unsigned short*)(ws + 159383552L);    // 0.52MB
    float*          BM    = (float*)(ws + 159907840L);             // 0.13MB
    float*          CM    = (float*)(ws + 160038912L);             // 0.13MB
    float*          TRS   = (float*)(ws + 160169984L);             // 1.05MB
    unsigned short* SSMP  = (unsigned short*)(ws + 161218560L);    // bf16 8 slabs 8.4MB (4-5)
    unsigned short* DTRAW = (unsigned short*)(ws + 161218560L);    // bf16 16.8MB (6-7)
    unsigned short* FFACT = (unsigned short*)(ws + 161218560L);    // bf16 23.1MB (11-12)
    float*          TRH   = (float*)(ws + 194772992L);             // f32 16.8MB (7)
    unsigned short* WGU   = (unsigned short*)(ws + 194772992L);    // bf16 46.1MB (10)
    unsigned short* YB    = (unsigned short*)(ws + 227803136L);    // bf16 16.8MB (7-8)
    unsigned short* HB    = XB;

    auto gemm = [&](const unsigned short* A, const unsigned short* Bt, void* C,
                    int M, int N, int K, int kch, int obf) {
        dim3 g(N / 128, M / 128, kch);
        gemm_bt<<<g, 256, 0, stream>>>(A, Bt, C, M, N, K, K / kch, obf);
    };
    auto gemm256 = [&](const unsigned short* A, const unsigned short* Bt, void* C,
                       int M, int N, int K, int kch, int obf) {
        dim3 g(N / 256, M / 256, kch);
        gemm_bt256<<<g, 512, 0, stream>>>(A, Bt, C, M, N, K, K / kch, obf);
    };
    auto cvt = [&](const float* x, unsigned short* y, long n) {
        cvt_bf16<<<(int)((n / 4 + 255) / 256), 256, 0, stream>>>(x, y, n);
    };

    // 1) x = rmsnorm(hs) -> bf16 ; w_in -> bf16
    cvt(w_in, WB, (long)2 * DI_ * H_);
    rmsnorm_cast<<<MROWS, 256, 0, stream>>>(hs, ln_in, XB);
    // 2) proj = x @ w_in^T -> bf16
    gemm256(XB, WB, PROJ, MROWS, 2 * DI_, H_, 1, 1);
    // 3) u = silu(conv(proj[:, :DI])) -> bf16 (4 ch/thread)
    conv_silu<<<(MROWS * DI_ / 4) / 256, 256, 0, stream>>>(PROJ, conv_w, conv_b, UB);
    // 4) ssm_p = u @ w_x^T (padded), split-K x8, bf16 slabs
    cvt_pad_wx<<<(256 * DI_ / 4) / 256, 256, 0, stream>>>(w_x, WB);
    gemm(UB, WB, SSMP, MROWS, 256, DI_, 8, 1);
    // 5) segment norms (bf16 slabs)
    ssm_norms<<<MROWS / 4, 256, 0, stream>>>(SSMP, dt_ln, b_ln, c_ln, TRB, BM, CM);
    // 6) dt_raw -> bf16
    cvt(w_dt, WB, (long)DI_ * R_);
    gemm(TRB, WB, DTRAW, MROWS, DI_, R_, 1, 1);
    // 7) selective scan v4
    scan_partA<<<(B_ * DI_ / 64) * PCH / 4, 256, 0, stream>>>(UB, DTRAW, b_dt, BM,
                                                              A_log, TRH, TRS);
    scan_combine<<<(B_ * DI_ * N_) / 256, 256, 0, stream>>>(A_log, TRS, TRH);
    scan_partC<<<(B_ * DI_ / 64) * PCH / 4, 256, 0, stream>>>(UB, DTRAW, b_dt, BM, CM,
                                                              A_log, Dskip, PROJ, TRH, YB);
    // 8) mixer, split-K x4, bf16 slabs
    cvt(w_out, WB, (long)H_ * DI_);
    gemm256(YB, WB, MIX, MROWS, H_, DI_, 4, 1);
    // 9) hidden + rmsnorm
    add_rmsnorm<<<MROWS, 256, 0, stream>>>(hs, MIX, ln_ff, HID, HB);
    // 10) combined gate+up GEMM (N=11264), split-K x2, bf16 slabs
    cvt(w_gate, WGU, (long)FF_ * H_);
    cvt(w_up, WGU + (long)FF_ * H_, (long)FF_ * H_);
    gemm256(HB, WGU, GFU, MROWS, 2 * FF_, H_, 2, 1);
    // 11) ffact = silu(gate)*up (sums 2 slabs) -> bf16
    silu_mul2<<<(int)(((long)MROWS * FF_ / 4 + 255) / 256), 256, 0, stream>>>(
        GFU, FFACT, (long)MROWS * FF_);
    // 12) ff = ffact @ w_down^T (split-K x4, bf16 slabs); out = hidden + sum(ff)
    cvt(w_down, WB, (long)H_ * FF_);
    gemm256(FFACT, WB, FFT, MROWS, H_, FF_, 4, 1);
    final_add<<<(int)(((long)MROWS * H_ / 4 + 255) / 256), 256, 0, stream>>>(
        HID, FFT, out, (long)MROWS * H_);
}

// Round 18
// 480.349 us; speedup vs baseline: 1.0191x; 1.0191x over previous
//
#include <hip/hip_runtime.h>
#include <stdint.h>

#define H_   2048
#define DI_  4096
#define N_   16
#define K_   4
#define R_   128
#define FF_  5632
#define B_   2
#define S_   1024
#define MROWS (B_*S_)   // 2048
#define PCH  32          // time chunks for scan
#define CSTEPS (S_/PCH)  // 32 steps per chunk

typedef float f32x4 __attribute__((ext_vector_type(4)));
typedef float f32x2 __attribute__((ext_vector_type(2)));
typedef __bf16 bf16x8 __attribute__((ext_vector_type(8)));

#define LOG2E 1.4426950408889634f
#define LN2   0.6931471805599453f

__device__ __forceinline__ unsigned short f2bf(float f) {
    union { float f; unsigned u; } v; v.f = f;
    unsigned r = v.u + 0x7fffu + ((v.u >> 16) & 1u);
    return (unsigned short)(r >> 16);
}

__device__ __forceinline__ float bf2f(unsigned short u) {
    union { unsigned u; float f; } v; v.u = ((unsigned)u) << 16;
    return v.f;
}

__device__ __forceinline__ float fexp2(float x) { return __builtin_amdgcn_exp2f(x); }
__device__ __forceinline__ float flog2(float x) { return __builtin_amdgcn_logf(x); }

__device__ __forceinline__ float softplus2(float v) {
    return (v > 20.f) ? v : LN2 * flog2(1.f + fexp2(v * LOG2E));
}

__device__ __forceinline__ void gload16(const void* g, void* lds) {
    __builtin_amdgcn_global_load_lds(
        (const __attribute__((address_space(1))) unsigned int*)(uintptr_t)g,
        (__attribute__((address_space(3))) unsigned int*)(unsigned int)(uintptr_t)lds,
        16, 0, 0);
}

// ---------------- GEMM 128x128 (for small-N shapes): C = A @ Bt^T ----------------
__global__ __launch_bounds__(256, 2)
void gemm_bt(const unsigned short* __restrict__ A, const unsigned short* __restrict__ Bt,
             void* __restrict__ Cv, int M, int N, int K, int Kc, int obf)
{
    __shared__ __align__(16) unsigned short As[128 * 64];
    __shared__ __align__(16) unsigned short Bs[128 * 64];
    const int t = threadIdx.x;
    const int l = t & 63;
    const int wv = t >> 6;

    int nwg = gridDim.x * gridDim.y;
    int wg = blockIdx.y * gridDim.x + blockIdx.x;
    if ((nwg & 7) == 0) {
        int q = nwg >> 3;
        wg = (wg & 7) * q + (wg >> 3);
    }
    const int bx = wg / gridDim.y;
    const int by = wg % gridDim.y;
    const long m0 = (long)by * 128;
    const long n0 = (long)bx * 128;
    const int wm = (wv >> 1) * 64;
    const int wn = (wv & 1) * 64;
    const long kstart = (long)blockIdx.z * Kc;
    const long cbase = (long)blockIdx.z * M * (long)N;

    f32x4 acc[4][4] = {};

    const int tr = t >> 3;
    const int cs = (t & 7) ^ (tr & 7);
    const unsigned short* gA = A + (m0 + tr) * (long)K + kstart + cs * 8;
    const unsigned short* gB = Bt + (n0 + tr) * (long)K + kstart + cs * 8;
    const unsigned ldsbase = (unsigned)(t & 192) * 16;

    for (int kt = 0; kt < Kc; kt += 64) {
#pragma unroll
        for (int j = 0; j < 4; ++j) {
            gload16(gA + (long)j * 32 * K, (char*)As + j * 4096 + ldsbase);
            gload16(gB + (long)j * 32 * K, (char*)Bs + j * 4096 + ldsbase);
        }
        gA += 64; gB += 64;
        __syncthreads();
#pragma unroll
        for (int k0 = 0; k0 < 2; ++k0) {
            bf16x8 af[4], bfr[4];
#pragma unroll
            for (int i = 0; i < 4; ++i) {
                int rowa = wm + i * 16 + (l & 15);
                int ca = (k0 * 4 + (l >> 4)) ^ (rowa & 7);
                af[i] = *(const bf16x8*)(As + rowa * 64 + ca * 8);
                int rowb = wn + i * 16 + (l & 15);
                int cb = (k0 * 4 + (l >> 4)) ^ (rowb & 7);
                bfr[i] = *(const bf16x8*)(Bs + rowb * 64 + cb * 8);
            }
#pragma unroll
            for (int i = 0; i < 4; ++i)
#pragma unroll
                for (int jn = 0; jn < 4; ++jn)
                    acc[i][jn] = __builtin_amdgcn_mfma_f32_16x16x32_bf16(
                        af[i], bfr[jn], acc[i][jn], 0, 0, 0);
        }
        __syncthreads();
    }

    const int crow = (l >> 4) * 4;
    const int ccol = l & 15;
    float* Cf = (float*)Cv + cbase;
    unsigned short* Cb = (unsigned short*)Cv + cbase;
#pragma unroll
    for (int i = 0; i < 4; ++i) {
#pragma unroll
        for (int jn = 0; jn < 4; ++jn) {
            long row = m0 + wm + i * 16 + crow;
            long col = n0 + wn + jn * 16 + ccol;
            if (obf) {
                unsigned short* cp = Cb + row * (long)N + col;
#pragma unroll
                for (int q = 0; q < 4; ++q) cp[(long)q * N] = f2bf(acc[i][jn][q]);
            } else {
                float* cp = Cf + row * (long)N + col;
#pragma unroll
                for (int q = 0; q < 4; ++q) cp[(long)q * N] = acc[i][jn][q];
            }
        }
    }
}

// ======== GEMM 256x256, 8 waves, BK=64, double-buffered, counted-vmcnt ========
// Best measured schedule: A(next) at tile top + vmcnt(4); B(next) mid-tile.
__global__ __launch_bounds__(512, 1)
void gemm_bt256(const unsigned short* __restrict__ A, const unsigned short* __restrict__ Bt,
                void* __restrict__ Cv, int M, int N, int K, int Kc, int obf)
{
    __shared__ __align__(16) unsigned short As[2][256 * 64];
    __shared__ __align__(16) unsigned short Bs[2][256 * 64];
    const int t = threadIdx.x;
    const int l = t & 63;
    const int wv = t >> 6;
    const int wm = wv >> 2;
    const int wn = wv & 3;

    int nwg = gridDim.x * gridDim.y;
    int wg = blockIdx.y * gridDim.x + blockIdx.x;
    if ((nwg & 7) == 0) {
        int q = nwg >> 3;
        wg = (wg & 7) * q + (wg >> 3);
    }
    const int bx = wg / gridDim.y;
    const int by = wg % gridDim.y;
    const long m0 = (long)by * 256;
    const long n0 = (long)bx * 256;
    const long kstart = (long)blockIdx.z * Kc;
    const long cbase = (long)blockIdx.z * M * (long)N;

    f32x4 acc[8][4] = {};

    const int cs = (t & 7) ^ ((t >> 3) & 7);
    const unsigned short* gA = A + (m0 + (t >> 3)) * (long)K + kstart + cs * 8;
    const unsigned short* gB = Bt + (n0 + (t >> 3)) * (long)K + kstart + cs * 8;
    const int NT = Kc >> 6;

#pragma unroll
    for (int i = 0; i < 4; ++i)
        gload16(gA + (long)i * 64 * K, &As[0][t * 8 + i * 4096]);
#pragma unroll
    for (int i = 0; i < 4; ++i)
        gload16(gB + (long)i * 64 * K, &Bs[0][t * 8 + i * 4096]);

    for (int kt = 0; kt < NT; ++kt) {
        const int buf = kt & 1;
        const long koff = (long)((kt + 1 < NT) ? (kt + 1) : kt) * 64;
#pragma unroll
        for (int i = 0; i < 4; ++i)
            gload16(gA + koff + (long)i * 64 * K, &As[buf ^ 1][t * 8 + i * 4096]);
        asm volatile("s_waitcnt vmcnt(4)" ::: "memory");
        __builtin_amdgcn_sched_barrier(0);
        __builtin_amdgcn_s_barrier();
        __builtin_amdgcn_sched_barrier(0);
        {
            bf16x8 af[8], bfr[4];
#pragma unroll
            for (int nf = 0; nf < 4; ++nf) {
                int rowb = wn * 64 + nf * 16 + (l & 15);
                int cb = (l >> 4) ^ (rowb & 7);
                bfr[nf] = *(const bf16x8*)(&Bs[buf][rowb * 64 + cb * 8]);
            }
#pragma unroll
            for (int mf = 0; mf < 8; ++mf) {
                int rowa = wm * 128 + mf * 16 + (l & 15);
                int ca = (l >> 4) ^ (rowa & 7);
                af[mf] = *(const bf16x8*)(&As[buf][rowa * 64 + ca * 8]);
            }
            __builtin_amdgcn_s_setprio(1);
#pragma unroll
            for (int mf = 0; mf < 8; ++mf)
#pragma unroll
                for (int nf = 0; nf < 4; ++nf)
                    acc[mf][nf] = __builtin_amdgcn_mfma_f32_16x16x32_bf16(
                        af[mf], bfr[nf], acc[mf][nf], 0, 0, 0);
            __builtin_amdgcn_s_setprio(0);
        }
        __builtin_amdgcn_sched_barrier(0);
#pragma unroll
        for (int i = 0; i < 4; ++i)
            gload16(gB + koff + (long)i * 64 * K, &Bs[buf ^ 1][t * 8 + i * 4096]);
        {
            bf16x8 af[8], bfr[4];
#pragma unroll
            for (int nf = 0; nf < 4; ++nf) {
                int rowb = wn * 64 + nf * 16 + (l & 15);
                int cb = (4 + (l >> 4)) ^ (rowb & 7);
                bfr[nf] = *(const bf16x8*)(&Bs[buf][rowb * 64 + cb * 8]);
            }
#pragma unroll
            for (int mf = 0; mf < 8; ++mf) {
                int rowa = wm * 128 + mf * 16 + (l & 15);
                int ca = (4 + (l >> 4)) ^ (rowa & 7);
                af[mf] = *(const bf16x8*)(&As[buf][rowa * 64 + ca * 8]);
            }
            __builtin_amdgcn_s_setprio(1);
#pragma unroll
            for (int mf = 0; mf < 8; ++mf)
#pragma unroll
                for (int nf = 0; nf < 4; ++nf)
                    acc[mf][nf] = __builtin_amdgcn_mfma_f32_16x16x32_bf16(
                        af[mf], bfr[nf], acc[mf][nf], 0, 0, 0);
            __builtin_amdgcn_s_setprio(0);
        }
        __builtin_amdgcn_sched_barrier(0);
        __builtin_amdgcn_s_barrier();
        __builtin_amdgcn_sched_barrier(0);
    }

    const int crow = (l >> 4) * 4;
    const int ccol = l & 15;
    float* Cf = (float*)Cv + cbase;
    unsigned short* Cb = (unsigned short*)Cv + cbase;
#pragma unroll
    for (int mf = 0; mf < 8; ++mf) {
#pragma unroll
        for (int nf = 0; nf < 4; ++nf) {
            long row = m0 + wm * 128 + mf * 16 + crow;
            long col = n0 + wn * 64 + nf * 16 + ccol;
            if (obf) {
                unsigned short* cp = Cb + row * (long)N + col;
#pragma unroll
                for (int q = 0; q < 4; ++q) cp[(long)q * N] = f2bf(acc[mf][nf][q]);
            } else {
                float* cp = Cf + row * (long)N + col;
#pragma unroll
                for (int q = 0; q < 4; ++q) cp[(long)q * N] = acc[mf][nf][q];
            }
        }
    }
}

// ---------------- f32 -> bf16 convert ----------------
__global__ __launch_bounds__(256)
void cvt_bf16(const float* __restrict__ x, unsigned short* __restrict__ y, long n)
{
    long i = ((long)blockIdx.x * 256 + threadIdx.x) * 4;
    if (i >= n) return;
    float4 v = *(const float4*)(x + i);
    ushort4 o;
    o.x = f2bf(v.x); o.y = f2bf(v.y); o.z = f2bf(v.z); o.w = f2bf(v.w);
    *(ushort4*)(y + i) = o;
}

// ---- two-source f32 -> bf16 convert (gate+up into contiguous dest) ----
__global__ __launch_bounds__(256)
void cvt_bf16_2(const float* __restrict__ x0, const float* __restrict__ x1,
                unsigned short* __restrict__ y, long n_each)
{
    long i = ((long)blockIdx.x * 256 + threadIdx.x) * 4;
    if (i >= 2 * n_each) return;
    const float* src = (i < n_each) ? (x0 + i) : (x1 + (i - n_each));
    float4 v = *(const float4*)src;
    ushort4 o;
    o.x = f2bf(v.x); o.y = f2bf(v.y); o.z = f2bf(v.z); o.w = f2bf(v.w);
    *(ushort4*)(y + i) = o;
}

// w_x [160,4096] -> bf16 padded to [256,4096] (zeros)
__global__ __launch_bounds__(256)
void cvt_pad_wx(const float* __restrict__ x, unsigned short* __restrict__ y)
{
    long i = ((long)blockIdx.x * 256 + threadIdx.x) * 4;
    int row = (int)(i >> 12);
    ushort4 o;
    if (row < 160) {
        float4 v = *(const float4*)(x + i);
        o.x = f2bf(v.x); o.y = f2bf(v.y); o.z = f2bf(v.z); o.w = f2bf(v.w);
    } else { o.x = 0; o.y = 0; o.z = 0; o.w = 0; }
    *(ushort4*)(y + i) = o;
}

// ---------------- RMSNorm over H=2048, output bf16 ----------------
__global__ __launch_bounds__(256)
void rmsnorm_cast(const float* __restrict__ x, const float* __restrict__ w,
                  unsigned short* __restrict__ out)
{
    const long row = blockIdx.x;
    const float* xr = x + row * H_ + threadIdx.x * 8;
    float4 v0 = *(const float4*)xr;
    float4 v1 = *(const float4*)(xr + 4);
    float xv[8] = {v0.x, v0.y, v0.z, v0.w, v1.x, v1.y, v1.z, v1.w};
    float s = 0.f;
#pragma unroll
    for (int j = 0; j < 8; ++j) s += xv[j] * xv[j];
#pragma unroll
    for (int m = 32; m; m >>= 1) s += __shfl_xor(s, m);
    __shared__ float red[4];
    if ((threadIdx.x & 63) == 0) red[threadIdx.x >> 6] = s;
    __syncthreads();
    s = red[0] + red[1] + red[2] + red[3];
    float inv = rsqrtf(s * (1.f / H_) + 1e-6f);
    const float* wr = w + threadIdx.x * 8;
    unsigned short* op = out + row * H_ + threadIdx.x * 8;
    ushort4 o0, o1;
    o0.x = f2bf(xv[0] * inv * wr[0]); o0.y = f2bf(xv[1] * inv * wr[1]);
    o0.z = f2bf(xv[2] * inv * wr[2]); o0.w = f2bf(xv[3] * inv * wr[3]);
    o1.x = f2bf(xv[4] * inv * wr[4]); o1.y = f2bf(xv[5] * inv * wr[5]);
    o1.z = f2bf(xv[6] * inv * wr[6]); o1.w = f2bf(xv[7] * inv * wr[7]);
    *(ushort4*)op = o0;
    *(ushort4*)(op + 4) = o1;
}

// --------- hidden = a + sum_4(mx bf16) ; h = rmsnorm(hidden) bf16 ----------
__global__ __launch_bounds__(256)
void add_rmsnorm(const float* __restrict__ a, const unsigned short* __restrict__ mx,
                 const float* __restrict__ w, float* __restrict__ hid,
                 unsigned short* __restrict__ hb)
{
    const long row = blockIdx.x;
    const long off = row * H_ + threadIdx.x * 8;
    float xv[8];
    {
        float4 a0 = *(const float4*)(a + off);
        float4 a1 = *(const float4*)(a + off + 4);
        xv[0] = a0.x; xv[1] = a0.y; xv[2] = a0.z; xv[3] = a0.w;
        xv[4] = a1.x; xv[5] = a1.y; xv[6] = a1.z; xv[7] = a1.w;
    }
#pragma unroll
    for (int z = 0; z < 4; ++z) {
        const unsigned short* mz = mx + (long)z * MROWS * H_ + off;
        ushort4 b0 = *(const ushort4*)mz;
        ushort4 b1 = *(const ushort4*)(mz + 4);
        xv[0] += bf2f(b0.x); xv[1] += bf2f(b0.y); xv[2] += bf2f(b0.z); xv[3] += bf2f(b0.w);
        xv[4] += bf2f(b1.x); xv[5] += bf2f(b1.y); xv[6] += bf2f(b1.z); xv[7] += bf2f(b1.w);
    }
    float s = 0.f;
#pragma unroll
    for (int j = 0; j < 8; ++j) s += xv[j] * xv[j];
#pragma unroll
    for (int m = 32; m; m >>= 1) s += __shfl_xor(s, m);
    __shared__ float red[4];
    if ((threadIdx.x & 63) == 0) red[threadIdx.x >> 6] = s;
    __syncthreads();
    s = red[0] + red[1] + red[2] + red[3];
    float inv = rsqrtf(s * (1.f / H_) + 1e-6f);
    float4 h0, h1;
    h0.x = xv[0]; h0.y = xv[1]; h0.z = xv[2]; h0.w = xv[3];
    h1.x = xv[4]; h1.y = xv[5]; h1.z = xv[6]; h1.w = xv[7];
    *(float4*)(hid + off) = h0;
    *(float4*)(hid + off + 4) = h1;
    const float* wr = w + threadIdx.x * 8;
    ushort4 o0, o1;
    o0.x = f2bf(xv[0] * inv * wr[0]); o0.y = f2bf(xv[1] * inv * wr[1]);
    o0.z = f2bf(xv[2] * inv * wr[2]); o0.w = f2bf(xv[3] * inv * wr[3]);
    o1.x = f2bf(xv[4] * inv * wr[4]); o1.y = f2bf(xv[5] * inv * wr[5]);
    o1.z = f2bf(xv[6] * inv * wr[6]); o1.w = f2bf(xv[7] * inv * wr[7]);
    *(ushort4*)(hb + off) = o0;
    *(ushort4*)(hb + off + 4) = o1;
}

// -------- causal depthwise conv(K=4) + bias + SiLU, 4 channels/thread --------
__global__ __launch_bounds__(256)
void conv_silu(const unsigned short* __restrict__ proj, const float* __restrict__ cw,
               const float* __restrict__ cb, unsigned short* __restrict__ ub)
{
    long i = ((long)blockIdx.x * 256 + threadIdx.x) * 4;
    int d = (int)(i & (DI_ - 1));
    long sd = i >> 12;
    int s = (int)(sd & (S_ - 1));
    long rb = sd * (2 * DI_) + d;
    ushort4 x0 = *(const ushort4*)(proj + rb);
    ushort4 x1 = {0, 0, 0, 0}, x2 = {0, 0, 0, 0}, x3 = {0, 0, 0, 0};
    if (s >= 1) x1 = *(const ushort4*)(proj + rb - 2 * DI_);
    if (s >= 2) x2 = *(const ushort4*)(proj + rb - 4 * DI_);
    if (s >= 3) x3 = *(const ushort4*)(proj + rb - 6 * DI_);
    float4 bias = *(const float4*)(cb + d);
    unsigned short xs0[4] = {x0.x, x0.y, x0.z, x0.w};
    unsigned short xs1[4] = {x1.x, x1.y, x1.z, x1.w};
    unsigned short xs2[4] = {x2.x, x2.y, x2.z, x2.w};
    unsigned short xs3[4] = {x3.x, x3.y, x3.z, x3.w};
    float bs[4] = {bias.x, bias.y, bias.z, bias.w};
    unsigned short os[4];
#pragma unroll
    for (int j = 0; j < 4; ++j) {
        float4 wj = *(const float4*)(cw + (d + j) * 4);
        float acc = bs[j] + wj.w * bf2f(xs0[j]);
        if (s >= 1) acc += wj.z * bf2f(xs1[j]);
        if (s >= 2) acc += wj.y * bf2f(xs2[j]);
        if (s >= 3) acc += wj.x * bf2f(xs3[j]);
        float r = acc / (1.f + __expf(-acc));
        os[j] = f2bf(r);
    }
    ushort4 o; o.x = os[0]; o.y = os[1]; o.z = os[2]; o.w = os[3];
    *(ushort4*)(ub + i) = o;
}

// ------ segment rmsnorms on ssm_p partial slabs (8 x [2048,256] bf16) ------
__global__ __launch_bounds__(256)
void ssm_norms(const unsigned short* __restrict__ ssmp, const float* __restrict__ wdt,
               const float* __restrict__ wb, const float* __restrict__ wc,
               unsigned short* __restrict__ trb, float* __restrict__ Bm,
               float* __restrict__ Cm)
{
    const long row = (long)blockIdx.x * 4 + (threadIdx.x >> 6);
    const int l = threadIdx.x & 63;
    float x0 = 0.f, x1 = 0.f, xb = 0.f, xc = 0.f;
#pragma unroll
    for (int z = 0; z < 8; ++z) {
        const unsigned short* rp = ssmp + (long)z * (MROWS * 256) + row * 256;
        x0 += bf2f(rp[l]);
        x1 += bf2f(rp[64 + l]);
        xb += bf2f(rp[128 + (l & 15)]);
        xc += bf2f(rp[144 + (l & 15)]);
    }
    float s = x0 * x0 + x1 * x1;
#pragma unroll
    for (int m = 32; m; m >>= 1) s += __shfl_xor(s, m);
    float inv = rsqrtf(s * (1.f / R_) + 1e-6f);
    trb[row * R_ + l] = f2bf(x0 * inv * wdt[l]);
    trb[row * R_ + 64 + l] = f2bf(x1 * inv * wdt[64 + l]);

    float sb = xb * xb, sc = xc * xc;
#pragma unroll
    for (int m = 8; m; m >>= 1) { sb += __shfl_xor(sb, m); sc += __shfl_xor(sc, m); }
    float invb = rsqrtf(sb * (1.f / N_) + 1e-6f);
    float invc = rsqrtf(sc * (1.f / N_) + 1e-6f);
    if (l < 16) {
        Bm[row * N_ + l] = xb * invb * wb[l];
        Cm[row * N_ + l] = xc * invc * wc[l];
    }
}

// =======================================================================
// Selective scan v4
// =======================================================================

__global__ __launch_bounds__(256)
void scan_partA(const unsigned short* __restrict__ ub, const unsigned short* __restrict__ dtraw,
                const float* __restrict__ bdt, const float* __restrict__ Bm,
                const float* __restrict__ A_log,
                float* __restrict__ TRH, float* __restrict__ TRS)
{
    const int w = __builtin_amdgcn_readfirstlane(threadIdx.x >> 6);
    const int l = threadIdx.x & 63;
    const int task = blockIdx.x * 4 + w;
    const int dchunk = task >> 5;
    const int p = task & 31;
    const int gch0 = dchunk * 64;
    const int batch = gch0 >> 12;
    const int d0 = gch0 & (DI_ - 1);
    const int d = d0 + l;
    const long bS = (long)batch * S_;
    const int t0 = p * CSTEPS;

    float Av2[16];
#pragma unroll
    for (int n = 0; n < 16; ++n)
        Av2[n] = -fexp2(A_log[(long)d * N_ + n] * LOG2E) * LOG2E;
    const float bias = bdt[d];

    float h[16];
#pragma unroll
    for (int n = 0; n < 16; ++n) h[n] = 0.f;
    float sdt = 0.f;

    float uN = bf2f(ub[(bS + t0) * DI_ + d]);
    float tN = bf2f(dtraw[(bS + t0) * DI_ + d]);
    float BN[16];
    {
        const float* Bp = Bm + (bS + t0) * N_;
#pragma unroll
        for (int n = 0; n < 16; ++n) BN[n] = Bp[n];
    }

    for (int s = 0; s < CSTEPS; ++s) {
        float uC = uN, tC = tN;
        float BC[16];
#pragma unroll
        for (int n = 0; n < 16; ++n) BC[n] = BN[n];
        if (s + 1 < CSTEPS) {
            long r2 = bS + t0 + s + 1;
            uN = bf2f(ub[r2 * DI_ + d]);
            tN = bf2f(dtraw[r2 * DI_ + d]);
            const float* Bp = Bm + r2 * N_;
#pragma unroll
            for (int n = 0; n < 16; ++n) BN[n] = Bp[n];
        }
        float dt = softplus2(tC + bias);
        float dtu = dt * uC;
        sdt += dt;
#pragma unroll
        for (int n = 0; n < 16; ++n) {
            float e = fexp2(dt * Av2[n]);
            h[n] = fmaf(e, h[n], dtu * BC[n]);
        }
    }
    float* hp = &TRH[(long)(gch0 + l) * (PCH * 16) + p * 16];
#pragma unroll
    for (int n = 0; n < 16; ++n) hp[n] = h[n];
    TRS[(long)(gch0 + l) * PCH + p] = sdt;
}

__global__ __launch_bounds__(256)
void scan_combine(const float* __restrict__ A_log, const float* __restrict__ TRS,
                  float* __restrict__ TRH)
{
    const int tid = blockIdx.x * 256 + threadIdx.x;
    const int gch = tid >> 4, n = tid & 15;
    const int d = gch & (DI_ - 1);
    const float Av = -__expf(A_log[(long)d * N_ + n]);
    const float* sp = TRS + (long)gch * PCH;
    float* hp = TRH + (long)gch * (PCH * 16) + n;
    float h = 0.f;
#pragma unroll
    for (int p = 0; p < PCH; ++p) {
        float hl = hp[p * 16];
        float e = __expf(Av * sp[p]);
        hp[p * 16] = h;
        h = hl + e * h;
    }
}

__global__ __launch_bounds__(256)
void scan_partC(const unsigned short* __restrict__ ub, const unsigned short* __restrict__ dtraw,
                const float* __restrict__ bdt, const float* __restrict__ Bm,
                const float* __restrict__ Cm, const float* __restrict__ A_log,
                const float* __restrict__ Dskip, const unsigned short* __restrict__ proj,
                const float* __restrict__ TRH, unsigned short* __restrict__ yb)
{
    const int w = __builtin_amdgcn_readfirstlane(threadIdx.x >> 6);
    const int l = threadIdx.x & 63;
    const int task = blockIdx.x * 4 + w;
    const int dchunk = task >> 5;
    const int p = task & 31;
    const int gch0 = dchunk * 64;
    const int batch = gch0 >> 12;
    const int d0 = gch0 & (DI_ - 1);
    const int d = d0 + l;
    const long bS = (long)batch * S_;
    const int t0 = p * CSTEPS;

    float Av2[16];
#pragma unroll
    for (int n = 0; n < 16; ++n)
        Av2[n] = -fexp2(A_log[(long)d * N_ + n] * LOG2E) * LOG2E;
    const float bias = bdt[d];
    const float Dv = Dskip[d];

    float h[16];
    {
        const float* hp = &TRH[(long)(gch0 + l) * (PCH * 16) + p * 16];
#pragma unroll
        for (int n = 0; n < 16; ++n) h[n] = hp[n];
    }

    float uN = bf2f(ub[(bS + t0) * DI_ + d]);
    float tN = bf2f(dtraw[(bS + t0) * DI_ + d]);
    float gN = bf2f(proj[(bS + t0) * (2L * DI_) + DI_ + d]);
    float BN[16], CN[16];
    {
        const float* Bp = Bm + (bS + t0) * N_;
        const float* Cp = Cm + (bS + t0) * N_;
#pragma unroll
        for (int n = 0; n < 16; ++n) { BN[n] = Bp[n]; CN[n] = Cp[n]; }
    }

    for (int s = 0; s < CSTEPS; ++s) {
        float uC = uN, tC = tN, gC = gN;
        float BC[16], CC_[16];
#pragma unroll
        for (int n = 0; n < 16; ++n) { BC[n] = BN[n]; CC_[n] = CN[n]; }
        if (s + 1 < CSTEPS) {
            long r2 = bS + t0 + s + 1;
            uN = bf2f(ub[r2 * DI_ + d]);
            tN = bf2f(dtraw[r2 * DI_ + d]);
            gN = bf2f(proj[r2 * (2L * DI_) + DI_ + d]);
            const float* Bp = Bm + r2 * N_;
            const float* Cp = Cm + r2 * N_;
#pragma unroll
            for (int n = 0; n < 16; ++n) { BN[n] = Bp[n]; CN[n] = Cp[n]; }
        }
        float dt = softplus2(tC + bias);
        float dtu = dt * uC;
        float y = uC * Dv;
#pragma unroll
        for (int n = 0; n < 16; ++n) {
            float e = fexp2(dt * Av2[n]);
            h[n] = fmaf(e, h[n], dtu * BC[n]);
            y = fmaf(h[n], CC_[n], y);
        }
        float eg = fexp2(-gC * LOG2E);
        float sl = gC * __builtin_amdgcn_rcpf(1.f + eg);
        yb[(bS + t0 + s) * DI_ + d] = f2bf(y * sl);
    }
}

// --- ffact = silu(gate)*up from combined gate/up GEMM (2 split-K slabs) ---
__global__ __launch_bounds__(256)
void silu_mul2(const unsigned short* __restrict__ gfu, unsigned short* __restrict__ out,
               long n)
{
    long i = ((long)blockIdx.x * 256 + threadIdx.x) * 4;
    if (i >= n) return;
    long m = i / FF_;
    int f = (int)(i - m * FF_);
    const long NW = 2L * FF_;
    const unsigned short* r0 = gfu + m * NW;
    const unsigned short* r1 = gfu + (long)MROWS * NW + m * NW;
    ushort4 g0 = *(const ushort4*)(r0 + f);
    ushort4 g1 = *(const ushort4*)(r1 + f);
    ushort4 u0 = *(const ushort4*)(r0 + FF_ + f);
    ushort4 u1 = *(const ushort4*)(r1 + FF_ + f);
    float gv[4] = {bf2f(g0.x) + bf2f(g1.x), bf2f(g0.y) + bf2f(g1.y),
                   bf2f(g0.z) + bf2f(g1.z), bf2f(g0.w) + bf2f(g1.w)};
    float uv[4] = {bf2f(u0.x) + bf2f(u1.x), bf2f(u0.y) + bf2f(u1.y),
                   bf2f(u0.z) + bf2f(u1.z), bf2f(u0.w) + bf2f(u1.w)};
    unsigned short os[4];
#pragma unroll
    for (int j = 0; j < 4; ++j)
        os[j] = f2bf(gv[j] / (1.f + __expf(-gv[j])) * uv[j]);
    ushort4 o; o.x = os[0]; o.y = os[1]; o.z = os[2]; o.w = os[3];
    *(ushort4*)(out + i) = o;
}

// ---------------- out = hidden + sum_4(ff bf16)  (split-K fuse) ----------------
__global__ __launch_bounds__(256)
void final_add(const float* __restrict__ a, const unsigned short* __restrict__ b,
               float* __restrict__ y, long n)
{
    long i = ((long)blockIdx.x * 256 + threadIdx.x) * 4;
    if (i >= n) return;
    float4 av = *(const float4*)(a + i);
    float4 o = av;
#pragma unroll
    for (int z = 0; z < 4; ++z) {
        ushort4 bv = *(const ushort4*)(b + (long)z * MROWS * H_ + i);
        o.x += bf2f(bv.x); o.y += bf2f(bv.y); o.z += bf2f(bv.z); o.w += bf2f(bv.w);
    }
    *(float4*)(y + i) = o;
}

extern "C" void kernel_launch(void* const* d_in, const int* in_sizes, int n_in,
                              void* d_out, int out_size, void* d_ws, size_t ws_size,
                              hipStream_t stream)
{
    const float* hs     = (const float*)d_in[0];
    const float* ln_in  = (const float*)d_in[1];
    const float* w_in   = (const float*)d_in[2];
    const float* conv_w = (const float*)d_in[3];
    const float* conv_b = (const float*)d_in[4];
    const float* w_x    = (const float*)d_in[5];
    const float* dt_ln  = (const float*)d_in[6];
    const float* b_ln   = (const float*)d_in[7];
    const float* c_ln   = (const float*)d_in[8];
    const float* w_dt   = (const float*)d_in[9];
    const float* b_dt   = (const float*)d_in[10];
    const float* A_log  = (const float*)d_in[11];
    const float* Dskip  = (const float*)d_in[12];
    const float* w_out  = (const float*)d_in[13];
    const float* ln_ff  = (const float*)d_in[14];
    const float* w_gate = (const float*)d_in[15];
    const float* w_up   = (const float*)d_in[16];
    const float* w_down = (const float*)d_in[17];
    float* out = (float*)d_out;
    char* ws = (char*)d_ws;

    // Arena (lifetime-based reuse)
    unsigned short* WB    = (unsigned short*)(ws + 0L);            // 33.5MB weights bf16
    unsigned short* XB    = (unsigned short*)(ws + 33554432L);     // 8.4MB (xb / hb)
    unsigned short* PROJ  = (unsigned short*)(ws + 41943040L);     // bf16 33.6MB (2-7)
    unsigned short* MIX   = (unsigned short*)(ws + 41943040L);     // bf16 4 slabs (8-9)
    unsigned short* GFU   = (unsigned short*)(ws + 41943040L);     // bf16 2 slabs 92.2MB (10-11)
    unsigned short* FFT   = (unsigned short*)(ws + 41943040L);     // bf16 4 slabs (12)
    unsigned short* UB    = (unsigned short*)(ws + 142606336L);    // bf16 16.8MB (3-7)
    float*          HID   = (float*)(ws + 142606336L);             // f32 16.8MB (9-12)
    unsigned short* TRB   = (unsigned short*)(ws + 159383552L);    // 0.52MB
    float*          BM    = (float*)(ws + 159907840L);             // 0.13MB
    float*          CM    = (float*)(ws + 160038912L);             // 0.13MB
    float*          TRS   = (float*)(ws + 160169984L);             // 1.05MB
    unsigned short* SSMP  = (unsigned short*)(ws + 161218560L);    // bf16 8 slabs 8.4MB (4-5)
    unsigned short* DTRAW = (unsigned short*)(ws + 161218560L);    // bf16 16.8MB (6-7)
    unsigned short* FFACT = (unsigned short*)(ws + 161218560L);    // bf16 23.1MB (11-12)
    float*          TRH   = (float*)(ws + 194772992L);             // f32 16.8MB (7)
    unsigned short* WGU   = (unsigned short*)(ws + 194772992L);    // bf16 46.1MB (10)
    unsigned short* YB    = (unsigned short*)(ws + 227803136L);    // bf16 16.8MB (7-8)
    unsigned short* HB    = XB;

    auto gemm = [&](const unsigned short* A, const unsigned short* Bt, void* C,
                    int M, int N, int K, int kch, int obf) {
        dim3 g(N / 128, M / 128, kch);
        gemm_bt<<<g, 256, 0, stream>>>(A, Bt, C, M, N, K, K / kch, obf);
    };
    auto gemm256 = [&](const unsigned short* A, const unsigned short* Bt, void* C,
                       int M, int N, int K, int kch, int obf) {
        dim3 g(N / 256, M / 256, kch);
        gemm_bt256<<<g, 512, 0, stream>>>(A, Bt, C, M, N, K, K / kch, obf);
    };
    auto cvt = [&](const float* x, unsigned short* y, long n) {
        cvt_bf16<<<(int)((n / 4 + 255) / 256), 256, 0, stream>>>(x, y, n);
    };

    // 1) x = rmsnorm(hs) -> bf16 ; w_in -> bf16
    cvt(w_in, WB, (long)2 * DI_ * H_);
    rmsnorm_cast<<<MROWS, 256, 0, stream>>>(hs, ln_in, XB);
    // 2) proj = x @ w_in^T -> bf16
    gemm256(XB, WB, PROJ, MROWS, 2 * DI_, H_, 1, 1);
    // 3) u = silu(conv(proj[:, :DI])) -> bf16 (4 ch/thread)
    conv_silu<<<(MROWS * DI_ / 4) / 256, 256, 0, stream>>>(PROJ, conv_w, conv_b, UB);
    // 4) ssm_p = u @ w_x^T (padded), split-K x8, bf16 slabs
    cvt_pad_wx<<<(256 * DI_ / 4) / 256, 256, 0, stream>>>(w_x, WB);
    gemm(UB, WB, SSMP, MROWS, 256, DI_, 8, 1);
    // 5) segment norms (bf16 slabs)
    ssm_norms<<<MROWS / 4, 256, 0, stream>>>(SSMP, dt_ln, b_ln, c_ln, TRB, BM, CM);
    // 6) dt_raw -> bf16
    cvt(w_dt, WB, (long)DI_ * R_);
    gemm(TRB, WB, DTRAW, MROWS, DI_, R_, 1, 1);
    // 7) selective scan v4
    scan_partA<<<(B_ * DI_ / 64) * PCH / 4, 256, 0, stream>>>(UB, DTRAW, b_dt, BM,
                                                              A_log, TRH, TRS);
    scan_combine<<<(B_ * DI_ * N_) / 256, 256, 0, stream>>>(A_log, TRS, TRH);
    scan_partC<<<(B_ * DI_ / 64) * PCH / 4, 256, 0, stream>>>(UB, DTRAW, b_dt, BM, CM,
                                                              A_log, Dskip, PROJ, TRH, YB);
    // 8) mixer, split-K x4, bf16 slabs
    cvt(w_out, WB, (long)H_ * DI_);
    gemm256(YB, WB, MIX, MROWS, H_, DI_, 4, 1);
    // 9) hidden + rmsnorm
    add_rmsnorm<<<MROWS, 256, 0, stream>>>(hs, MIX, ln_ff, HID, HB);
    // 10) combined gate+up GEMM (N=11264), split-K x2, bf16 slabs
    cvt_bf16_2<<<(int)(((long)2 * FF_ * H_ / 4 + 255) / 256), 256, 0, stream>>>(
        w_gate, w_up, WGU, (long)FF_ * H_);
    gemm256(HB, WGU, GFU, MROWS, 2 * FF_, H_, 2, 1);
    // 11) ffact = silu(gate)*up (sums 2 slabs) -> bf16
    silu_mul2<<<(int)(((long)MROWS * FF_ / 4 + 255) / 256), 256, 0, stream>>>(
        GFU, FFACT, (long)MROWS * FF_);
    // 12) ff = ffact @ w_down^T (split-K x4, bf16 slabs); out = hidden + sum(ff)
    cvt(w_down, WB, (long)H_ * FF_);
    gemm256(FFACT, WB, FFT, MROWS, H_, FF_, 4, 1);
    final_add<<<(int)(((long)MROWS * H_ / 4 + 255) / 256), 256, 0, stream>>>(
        HID, FFT, out, (long)MROWS * H_);
}